// Round 2
// baseline (5531.639 us; speedup 1.0000x reference)
//
#include <hip/hip_runtime.h>
#include <math.h>

#define EMBD 128
#define HIDD 128
#define NTAR 16
#define BSEQ 4096
#define G4   (4 * HIDD)   // 512 gate pre-activations per step

// ---------------------------------------------------------------------------
// Kernel 1: input projection (parallel over all timesteps)
// zx[t][j] = dot(emb[x[t]], w_ih[j]) + b_ih[j] + b_hh[j]
// ---------------------------------------------------------------------------
__global__ void input_proj_kernel(const int* __restrict__ x,
                                  const float* __restrict__ emb,
                                  const float* __restrict__ w_ih,
                                  const float* __restrict__ b_ih,
                                  const float* __restrict__ b_hh,
                                  float* __restrict__ zx) {
    const int t = blockIdx.x;
    const int j = threadIdx.x;            // 0..511
    const int idx = x[t];
    const float4* __restrict__ er = (const float4*)(emb + (long long)idx * EMBD);
    const float4* __restrict__ wr = (const float4*)(w_ih + j * EMBD);
    float acc = 0.f;
#pragma unroll
    for (int k = 0; k < EMBD / 4; ++k) {
        float4 e = er[k];
        float4 w = wr[k];
        acc += e.x * w.x + e.y * w.y + e.z * w.z + e.w * w.w;
    }
    zx[t * G4 + j] = acc + b_ih[j] + b_hh[j];
}

// ---------------------------------------------------------------------------
// Kernel 2: sequential LSTM, one workgroup of 256 threads (4 waves, 1/SIMD).
//
// R1 was LDS-broadcast-bound: 512 threads each broadcast-reading all 128 h
// floats = 256 KB/step of LDS return traffic ≈ 2048 cyc/step. New layout:
//   wave q (= threadIdx/64) owns k-quarter [32q, 32q+32) of h;
//   lane l computes partial dots for 8 rows {l + 64m}, weights in 256 VGPRs.
// LDS h-traffic drops 8x to 32 KB/step (~256 cyc); VALU (256 fma/thread,
// ~512 cyc/SIMD) becomes the floor.
// Phase B (threads 0..127): sum 4 quarter-partials per gate (LDS, stride-1,
// conflict-free), add precomputed zx, nonlinearities, c/h update.
// zx prefetched 2 steps ahead to cover ~900cyc HBM latency.
// ---------------------------------------------------------------------------
__global__ __launch_bounds__(256, 1)
void lstm_seq_kernel(const float* __restrict__ zx,
                     const float* __restrict__ w_hh,
                     float* __restrict__ hs) {
    __shared__ float h_sh[HIDD];
    __shared__ float part_sh[4 * G4];   // [quarter][row], 8 KB

    const int tid = threadIdx.x;
    const int l   = tid & 63;
    const int q   = tid >> 6;           // wave index = k-quarter

    // Preload weights: rows {l + 64m}, cols [32q, 32q+32)  -> 256 VGPRs.
    float4 w[8][8];
#pragma unroll
    for (int m = 0; m < 8; ++m) {
        const float4* __restrict__ wr =
            (const float4*)(w_hh + (l + 64 * m) * HIDD + 32 * q);
#pragma unroll
        for (int k = 0; k < 8; ++k) w[m][k] = wr[k];
    }

    if (tid < HIDD) h_sh[tid] = 0.f;
    float c = 0.f;

    // zx prefetch registers (phase-B threads only), 2 steps deep.
    float zn_cur[4], zn_nxt[4];
    if (tid < HIDD) {
#pragma unroll
        for (int g = 0; g < 4; ++g) zn_cur[g] = zx[0 * G4 + tid + 128 * g];
#pragma unroll
        for (int g = 0; g < 4; ++g) zn_nxt[g] = zx[1 * G4 + tid + 128 * g];
    }
    __syncthreads();

    const float4* hq = (const float4*)(h_sh) + q * 8;   // this wave's h quarter

    for (int t = 0; t < BSEQ; ++t) {
        // Issue prefetch for step t+2 (independent of everything below).
        float zn_fut[4];
        if (tid < HIDD) {
            const int tf = (t + 2 < BSEQ) ? (t + 2) : (BSEQ - 1);
#pragma unroll
            for (int g = 0; g < 4; ++g) zn_fut[g] = zx[tf * G4 + tid + 128 * g];
        }

        // Partial dots: 8 rows x 32-wide k-quarter. 8 independent FMA chains.
        float acc[8];
#pragma unroll
        for (int m = 0; m < 8; ++m) acc[m] = 0.f;
#pragma unroll
        for (int k = 0; k < 8; ++k) {
            const float4 hv = hq[k];                    // b128 broadcast
#pragma unroll
            for (int m = 0; m < 8; ++m)
                acc[m] += hv.x * w[m][k].x + hv.y * w[m][k].y
                        + hv.z * w[m][k].z + hv.w * w[m][k].w;
        }
        // Write partials: addr = q*512 + l + 64m -> lanes stride-1, 2-way
        // bank aliasing only (free on CDNA4).
#pragma unroll
        for (int m = 0; m < 8; ++m)
            part_sh[q * G4 + l + 64 * m] = acc[m];
        __syncthreads();

        // Phase B: combine quarters, gates, state update.
        if (tid < HIDD) {
            float zg[4];
#pragma unroll
            for (int g = 0; g < 4; ++g) {
                float s = zn_cur[g];
#pragma unroll
                for (int qq = 0; qq < 4; ++qq)
                    s += part_sh[qq * G4 + tid + 128 * g];
                zg[g] = s;
            }
            const float gi = 1.f / (1.f + expf(-zg[0]));
            const float gf = 1.f / (1.f + expf(-zg[1]));
            const float gg = tanhf(zg[2]);
            const float go = 1.f / (1.f + expf(-zg[3]));
            c = gf * c + gi * gg;
            const float h = go * tanhf(c);
            h_sh[tid] = h;
            hs[t * HIDD + tid] = h;     // fire-and-forget
        }
        __syncthreads();

#pragma unroll
        for (int g = 0; g < 4; ++g) { zn_cur[g] = zn_nxt[g]; zn_nxt[g] = zn_fut[g]; }
    }
}

// ---------------------------------------------------------------------------
// Kernel 3: final FC. out[t][n] = dot(hs[t], w_fc[n]) + b_fc[n].
// ---------------------------------------------------------------------------
__global__ void fc_kernel(const float* __restrict__ hs,
                          const float* __restrict__ w_fc,
                          const float* __restrict__ b_fc,
                          float* __restrict__ out) {
    const int gid = blockIdx.x * blockDim.x + threadIdx.x;
    if (gid >= BSEQ * NTAR) return;
    const int n = gid & (NTAR - 1);
    const int t = gid >> 4;
    const float4* __restrict__ hr = (const float4*)(hs + t * HIDD);
    const float4* __restrict__ wr = (const float4*)(w_fc + n * HIDD);
    float acc = 0.f;
#pragma unroll
    for (int k = 0; k < HIDD / 4; ++k) {
        float4 h = hr[k];
        float4 wv = wr[k];
        acc += h.x * wv.x + h.y * wv.y + h.z * wv.z + h.w * wv.w;
    }
    out[gid] = acc + b_fc[n];
}

// ---------------------------------------------------------------------------
extern "C" void kernel_launch(void* const* d_in, const int* in_sizes, int n_in,
                              void* d_out, int out_size, void* d_ws, size_t ws_size,
                              hipStream_t stream) {
    const int*   x    = (const int*)d_in[0];
    const float* emb  = (const float*)d_in[1];
    const float* w_ih = (const float*)d_in[2];
    const float* w_hh = (const float*)d_in[3];
    const float* b_ih = (const float*)d_in[4];
    const float* b_hh = (const float*)d_in[5];
    const float* w_fc = (const float*)d_in[6];
    const float* b_fc = (const float*)d_in[7];
    float* out = (float*)d_out;

    // Workspace layout: zx (4096*512 f32 = 8 MB) | hs (4096*128 f32 = 2 MB)
    float* zx = (float*)d_ws;
    float* hs = zx + (size_t)BSEQ * G4;

    input_proj_kernel<<<BSEQ, G4, 0, stream>>>(x, emb, w_ih, b_ih, b_hh, zx);
    lstm_seq_kernel<<<1, 256, 0, stream>>>(zx, w_hh, hs);
    fc_kernel<<<(BSEQ * NTAR + 255) / 256, 256, 0, stream>>>(hs, w_fc, b_fc, out);
}

// Round 4
// 2881.483 us; speedup vs baseline: 1.9197x; 1.9197x over previous
//
#include <hip/hip_runtime.h>
#include <math.h>

#define EMBD 128
#define HIDD 128
#define NTAR 16
#define BSEQ 4096
#define G4   (4 * HIDD)   // 512 gate pre-activations per step
#define CH   8            // time-chunk: amortizes the vmcnt(0) drain that
                          // __syncthreads forces (one zx-load stall per 8
                          // steps instead of per step)

typedef float v2f __attribute__((ext_vector_type(2)));

__device__ __forceinline__ float fast_sigmoid(float z) {
    return __builtin_amdgcn_rcpf(1.f + __expf(-z));
}
__device__ __forceinline__ float fast_tanh(float z) {
    // tanh(z) = 1 - 2/(exp(2z)+1); saturates correctly at +-1.
    return 1.f - 2.f * __builtin_amdgcn_rcpf(1.f + __expf(2.f * z));
}

// ---------------------------------------------------------------------------
// Kernel 1: input projection, TRANSPOSED output layout.
// zxT[(t*128 + u)*4 + g] = dot(emb[x[t]], w_ih[g*128+u]) + b_ih[.] + b_hh[.]
// Thread j -> (u = j>>2, g = j&3), so the write is fully coalesced and the
// LSTM's phase-B thread `u` reads its 4 gate biases as ONE float4.
// ---------------------------------------------------------------------------
__global__ void input_proj_kernel(const int* __restrict__ x,
                                  const float* __restrict__ emb,
                                  const float* __restrict__ w_ih,
                                  const float* __restrict__ b_ih,
                                  const float* __restrict__ b_hh,
                                  float* __restrict__ zxT) {
    const int t = blockIdx.x;
    const int j = threadIdx.x;            // 0..511
    const int u = j >> 2;
    const int g = j & 3;
    const int row = g * HIDD + u;
    const int idx = x[t];
    const float4* __restrict__ er = (const float4*)(emb + (long long)idx * EMBD);
    const float4* __restrict__ wr = (const float4*)(w_ih + row * EMBD);
    float acc = 0.f;
#pragma unroll
    for (int k = 0; k < EMBD / 4; ++k) {
        float4 e = er[k];
        float4 w = wr[k];
        acc += e.x * w.x + e.y * w.y + e.z * w.z + e.w * w.w;
    }
    zxT[(t * HIDD + u) * 4 + g] = acc + b_ih[row] + b_hh[row];
}

// ---------------------------------------------------------------------------
// Kernel 2: sequential LSTM. One workgroup, 512 threads (8 waves, 2/SIMD).
// Real __syncthreads() everywhere (R3's lgkmcnt-only asm barrier caused
// post-timing divergence — a race; never again).
//
// Thread layout: l=tid&63, wave=tid>>6; k-quarter q=wave&3, unit-half
// rg=wave>>2, unit u=l+64*rg. Thread owns gate rows {u+128g} of W_hh over
// cols [32q,32q+32) as 64 v2f pairs, PINNED in VGPRs via opaque asm
// (R2 post-mortem: unpinned weights get rematerialized -> 256 KB/step
// re-streamed). v2f math -> v_pk_fma_f32, halving phase-A VALU cycles.
//
// Time loop chunked by CH=8: chunk top (a) stores previous chunk's 8 h
// values, (b) loads this chunk's 8 zx float4s into registers. Both are
// force-drained by the first __syncthreads ~500 cyc later — one exposed
// HBM stall per chunk instead of per step.
// ---------------------------------------------------------------------------
__global__ __launch_bounds__(512, 2)
void lstm_seq_kernel(const float* __restrict__ zxT,
                     const float* __restrict__ w_hh,
                     float* __restrict__ hs) {
    __shared__ float h_sh[HIDD];
    __shared__ float part_sh[4 * G4];   // [quarter][gate][unit], 8 KB

    const int tid = threadIdx.x;
    const int l   = tid & 63;
    const int wv  = tid >> 6;
    const int q   = wv & 3;             // k-quarter
    const int rg  = wv >> 2;            // unit half
    const int u   = l + 64 * rg;        // hidden unit 0..127

    // Preload weights as packed pairs: w2[g][k] = W_hh[u+128g][32q+2k .. +1].
    v2f w2[4][16];
#pragma unroll
    for (int g = 0; g < 4; ++g) {
        const float4* __restrict__ wr =
            (const float4*)(w_hh + (u + 128 * g) * HIDD + 32 * q);
#pragma unroll
        for (int k4 = 0; k4 < 8; ++k4) {
            float4 v = wr[k4];
            w2[g][2 * k4 + 0] = (v2f){v.x, v.y};
            w2[g][2 * k4 + 1] = (v2f){v.z, v.w};
        }
    }
    // Pin: opaque asm result cannot be rematerialized -> stays in VGPRs.
#pragma unroll
    for (int g = 0; g < 4; ++g)
#pragma unroll
        for (int k = 0; k < 16; ++k)
            asm volatile("" : "+v"(w2[g][k]));

    if (tid < HIDD) h_sh[tid] = 0.f;
    float c = 0.f;
    float4 zreg[CH];    // this chunk's zx rows (phase-B threads)
    float  hreg[CH];    // this chunk's h outputs, stored at next chunk top
#pragma unroll
    for (int s = 0; s < CH; ++s) { zreg[s] = make_float4(0,0,0,0); hreg[s] = 0.f; }
    __syncthreads();

    const float4* hq = (const float4*)h_sh + q * 8;   // this wave's h quarter
    const float4* __restrict__ zx4 = (const float4*)zxT;

    for (int tc = 0; tc < BSEQ; tc += CH) {
        if (tid < HIDD) {
            if (tc > 0) {
#pragma unroll
                for (int s = 0; s < CH; ++s)
                    hs[(tc - CH + s) * HIDD + tid] = hreg[s];
            }
#pragma unroll
            for (int s = 0; s < CH; ++s)
                zreg[s] = zx4[(tc + s) * HIDD + tid];
        }

#pragma unroll
        for (int s = 0; s < CH; ++s) {
            // Phase A: 4 gate-row partial dots, packed fp32 FMAs.
            v2f a2[4] = {(v2f){0.f,0.f},(v2f){0.f,0.f},(v2f){0.f,0.f},(v2f){0.f,0.f}};
#pragma unroll
            for (int k4 = 0; k4 < 8; ++k4) {
                const float4 hv = hq[k4];           // broadcast b128 read
                const v2f hlo = (v2f){hv.x, hv.y};
                const v2f hhi = (v2f){hv.z, hv.w};
#pragma unroll
                for (int g = 0; g < 4; ++g) {
                    a2[g] += hlo * w2[g][2 * k4 + 0];   // -> v_pk_fma_f32
                    a2[g] += hhi * w2[g][2 * k4 + 1];
                }
            }
#pragma unroll
            for (int g = 0; g < 4; ++g)
                part_sh[q * G4 + g * HIDD + u] = a2[g].x + a2[g].y;
            __syncthreads();

            // Phase B: combine quarters, gates, state update (threads 0..127).
            if (tid < HIDD) {
                const float4 z4 = zreg[s];
                float zi = z4.x, zf = z4.y, zg = z4.z, zo = z4.w;
#pragma unroll
                for (int qq = 0; qq < 4; ++qq) {
                    zi += part_sh[qq * G4 + 0 * HIDD + tid];
                    zf += part_sh[qq * G4 + 1 * HIDD + tid];
                    zg += part_sh[qq * G4 + 2 * HIDD + tid];
                    zo += part_sh[qq * G4 + 3 * HIDD + tid];
                }
                const float gi = fast_sigmoid(zi);
                const float gf = fast_sigmoid(zf);
                const float gg = fast_tanh(zg);
                const float go = fast_sigmoid(zo);
                c = gf * c + gi * gg;
                const float h = go * fast_tanh(c);
                h_sh[tid] = h;
                hreg[s] = h;
            }
            __syncthreads();
        }
    }
    // Epilogue: last chunk's h values.
    if (tid < HIDD) {
#pragma unroll
        for (int s = 0; s < CH; ++s)
            hs[(BSEQ - CH + s) * HIDD + tid] = hreg[s];
    }
}

// ---------------------------------------------------------------------------
// Kernel 3: final FC. out[t][n] = dot(hs[t], w_fc[n]) + b_fc[n].
// ---------------------------------------------------------------------------
__global__ void fc_kernel(const float* __restrict__ hs,
                          const float* __restrict__ w_fc,
                          const float* __restrict__ b_fc,
                          float* __restrict__ out) {
    const int gid = blockIdx.x * blockDim.x + threadIdx.x;
    if (gid >= BSEQ * NTAR) return;
    const int n = gid & (NTAR - 1);
    const int t = gid >> 4;
    const float4* __restrict__ hr = (const float4*)(hs + t * HIDD);
    const float4* __restrict__ wr = (const float4*)(w_fc + n * HIDD);
    float acc = 0.f;
#pragma unroll
    for (int k = 0; k < HIDD / 4; ++k) {
        float4 h = hr[k];
        float4 wv = wr[k];
        acc += h.x * wv.x + h.y * wv.y + h.z * wv.z + h.w * wv.w;
    }
    out[gid] = acc + b_fc[n];
}

// ---------------------------------------------------------------------------
extern "C" void kernel_launch(void* const* d_in, const int* in_sizes, int n_in,
                              void* d_out, int out_size, void* d_ws, size_t ws_size,
                              hipStream_t stream) {
    const int*   x    = (const int*)d_in[0];
    const float* emb  = (const float*)d_in[1];
    const float* w_ih = (const float*)d_in[2];
    const float* w_hh = (const float*)d_in[3];
    const float* b_ih = (const float*)d_in[4];
    const float* b_hh = (const float*)d_in[5];
    const float* w_fc = (const float*)d_in[6];
    const float* b_fc = (const float*)d_in[7];
    float* out = (float*)d_out;

    // Workspace layout: zxT (4096*512 f32 = 8 MB) | hs (4096*128 f32 = 2 MB)
    float* zxT = (float*)d_ws;
    float* hs  = zxT + (size_t)BSEQ * G4;

    input_proj_kernel<<<BSEQ, G4, 0, stream>>>(x, emb, w_ih, b_ih, b_hh, zxT);
    lstm_seq_kernel<<<1, 512, 0, stream>>>(zxT, w_hh, hs);
    fc_kernel<<<(BSEQ * NTAR + 255) / 256, 256, 0, stream>>>(hs, w_fc, b_fc, out);
}